// Round 14
// baseline (149.228 us; speedup 1.0000x reference)
//
#include <hip/hip_runtime.h>
#include <hip/hip_bf16.h>

#define B_ 4
#define C_ 128
#define N_ 4096
#define M_ 4096

typedef __bf16 bf16;
typedef __bf16 bf16x8 __attribute__((ext_vector_type(8)));
typedef float f32x4 __attribute__((ext_vector_type(4)));
typedef float f32x16 __attribute__((ext_vector_type(16)));
typedef unsigned u32x2 __attribute__((ext_vector_type(2)));

#define MFMA16(a, b, c) __builtin_amdgcn_mfma_f32_16x16x32_bf16(a, b, c, 0, 0, 0)
#define MFMA32(a, b, c) __builtin_amdgcn_mfma_f32_32x32x16_bf16(a, b, c, 0, 0, 0)

// async 16B global -> LDS (dest = wave-uniform base + lane*16)
__device__ inline void gll16(const bf16* g, bf16* l) {
    __builtin_amdgcn_global_load_lds(
        (const __attribute__((address_space(1))) void*)g,
        (__attribute__((address_space(3))) void*)l, 16, 0, 0);
}

// v_cvt_pk_bf16_f32: pack two f32 -> u32 of 2 bf16 (lo = a, hi = b)
__device__ inline unsigned cvtpk(float a, float b) {
    unsigned r;
    asm("v_cvt_pk_bf16_f32 %0, %1, %2" : "=v"(r) : "v"(a), "v"(b));
    return r;
}

// ===========================================================================
// Kernel 0: W f32->bf16 into head of d_ws. Wq pre-scaled by KS (r12).
// ===========================================================================
__global__ __launch_bounds__(256) void wcvt_kernel(
    const float* __restrict__ Wq, const float* __restrict__ Wk,
    const float* __restrict__ Wv, bf16* __restrict__ Wb) {
    int i = (blockIdx.x * 256 + threadIdx.x) * 4;        // 49152 elements total
    const float* src = (i < 16384) ? Wq : (i < 32768) ? Wk : Wv;
    float scale = (i < 16384) ? 0.12752107168406815f : 1.0f;
    int off = i & 16383;
    float4 v = *(const float4*)(src + off);
    union { ushort4 u4; bf16 h[4]; } pk;
    pk.h[0] = (bf16)(v.x * scale); pk.h[1] = (bf16)(v.y * scale);
    pk.h[2] = (bf16)(v.z * scale); pk.h[3] = (bf16)(v.w * scale);
    *(ushort4*)(Wb + i) = pk.u4;
}

// ===========================================================================
// Kernel 1: fused K+V projection at 2 blocks/CU (UNCHANGED — r13 verified).
// ===========================================================================
__global__ __launch_bounds__(256) void kvproj_kernel(
    const float* __restrict__ x2, const float* __restrict__ p2,
    const bf16* __restrict__ Wb, const float* __restrict__ Wpos,
    bf16* __restrict__ Kt, bf16* __restrict__ Vt) {
    __shared__ __align__(16) bf16 xp2[32 * 136];   // x2 + pos  [n][c]
    __shared__ __align__(16) bf16 xr2[32 * 136];   // x2 raw
    __shared__ float pp[3 * 32], wls[384];

    const int t = threadIdx.x;
    const int b = blockIdx.y;
    const int n0 = blockIdx.x * 32;

    if (t < 24) {
        int k3 = t / 8, i4 = (t & 7) * 4;
        *(float4*)&pp[k3 * 32 + i4] =
            *(const float4*)(p2 + ((size_t)b * 3 + k3) * N_ + n0 + i4);
    } else if (t < 120) {
        int i4 = (t - 24) * 4;
        *(float4*)&wls[i4] = *(const float4*)(Wpos + i4);
    }
    __syncthreads();

    #pragma unroll
    for (int k = 0; k < 4; ++k) {
        int s = t + k * 256;
        int c = s >> 3, n4 = (s & 7) * 4;
        float4 xv = *(const float4*)(x2 + ((size_t)b * C_ + c) * N_ + n0 + n4);
        float w0 = wls[c * 3 + 0], w1 = wls[c * 3 + 1], w2 = wls[c * 3 + 2];
        const float* xa = &xv.x;
        #pragma unroll
        for (int j = 0; j < 4; ++j) {
            float pos = w0 * pp[n4 + j] + w1 * pp[32 + n4 + j] + w2 * pp[64 + n4 + j];
            xp2[(n4 + j) * 136 + c] = (bf16)(xa[j] + pos);
            xr2[(n4 + j) * 136 + c] = (bf16)xa[j];
        }
    }
    __syncthreads();

    const int w = t >> 6;
    const int lane = t & 63;
    const int col = lane & 15, quad = lane >> 4;
    const int band = w & 1;
    const int nl = band * 16 + col;
    const bool isK = (w < 2);

    const bf16* src = isK ? xp2 : xr2;
    const bf16* Wm = Wb + (isK ? 16384 : 32768);   // Wk / Wv

    bf16x8 bx[4];
    #pragma unroll
    for (int cs = 0; cs < 4; ++cs)
        bx[cs] = *(const bf16x8*)&src[nl * 136 + cs * 32 + quad * 8];

    if (isK) {
        #pragma unroll
        for (int dt = 0; dt < 8; ++dt) {
            f32x4 acc = {0.f, 0.f, 0.f, 0.f};
            #pragma unroll
            for (int cs = 0; cs < 4; ++cs) {
                bf16x8 wf = *(const bf16x8*)(Wm + (dt * 16 + col) * 128 + cs * 32 + quad * 8);
                acc = MFMA16(bx[cs], wf, acc);        // D[m-rows][c-cols]
            }
            #pragma unroll
            for (int r = 0; r < 4; ++r) {
                int n = n0 + band * 16 + quad * 4 + r;
                Kt[((size_t)b * N_ + n) * C_ + dt * 16 + col] = (bf16)acc[r];
            }
        }
    } else {
        #pragma unroll
        for (int dt = 0; dt < 8; ++dt) {
            f32x4 acc = {0.f, 0.f, 0.f, 0.f};
            #pragma unroll
            for (int cs = 0; cs < 4; ++cs) {
                bf16x8 wf = *(const bf16x8*)(Wm + (dt * 16 + col) * 128 + cs * 32 + quad * 8);
                acc = MFMA16(wf, bx[cs], acc);        // D[c-rows][m-cols]
            }
            #pragma unroll
            for (int r = 0; r < 4; ++r)
                Vt[((size_t)b * C_ + dt * 16 + quad * 4 + r) * (size_t)M_ + n0 + nl] = (bf16)acc[r];
        }
    }
}

// ===========================================================================
// Kernel 2 (v8): 32-QUERY blocks, 8 DISTINCT key-groups, 256-key chunks.
// Rationale (r13 pipe ledger): LDS ~2000 cyc/chunk was the largest pipe and
// the 2-qg structure read every K/V LDS byte TWICE. Here each wave owns keys
// w*32..+31 -> every byte read once (ds_read/key halves) AND K is fully
// wave-private (stage==read rows) -> QK needs NO barrier. Body:
//   vmcnt(8)[own K] -> QK -> lgkm fence -> stageK(next) -> SM ->
//   vmcnt(8 or 0)[V] -> barrier -> PV -> lgkm fence -> barrier -> stageV(next)
// Single-buffered K (64KB) + V (64KB); the barrier-free QK/SM stretch lets
// SIMD-sibling waves skew (MFMA || VALU overlap). Grid 512 (2 clean rounds).
// All SM/transpose/PV formulas carried from the r12/r13-verified kernel
// (kg := w; V-slot swizzle ^(c&31) preserves vaddrB = vaddrA^32, +ct*16384).
// Cost accepted: K/V L2 re-read x2 (ages >= 1200 cyc cover it), prologue x2.
// ===========================================================================
__global__ __launch_bounds__(512) void attn_kernel(
    const bf16* __restrict__ Kt, const bf16* __restrict__ Vt,
    const float* __restrict__ x1, const float* __restrict__ p1,
    const bf16* __restrict__ Wb, const float* __restrict__ Wpos,
    float* __restrict__ out) {
    __shared__ __align__(16) char smem[132096];
    // kb @0 (64KB, [256 key][16 slots ^ key&15]);
    // vb @65536 (64KB, [128 c][32 slots ^ c&31]);
    // epilogue: obuf @0 (128KB), lps @131072 (1KB)

    const int t = threadIdx.x;
    const int w = t >> 6;            // wave = key-group (32 keys of 256)
    const int lane = t & 63;
    const int col = lane & 31;
    const int hi = lane >> 5;

    const int g0 = blockIdx.x;
    const int xcd = g0 & 7;
    const int b = xcd >> 1;
    const int qt = (xcd & 1) + ((g0 >> 3) << 1);   // 128 q-tiles of 32
    const int n0 = qt * 32;

    const bf16* Kbase = Kt + (size_t)b * M_ * C_;
    const bf16* Vbase = Vt + (size_t)b * C_ * M_;

    // ======================= Q-projection prologue (32 q) ================
    bf16* xq = (bf16*)smem;                    // [32][136]
    float* ppq = (float*)(smem + 8704);
    float* wlsq = (float*)(smem + 9216);

    if (t < 24) {
        int k3 = t / 8, i4 = (t & 7) * 4;
        *(float4*)&ppq[k3 * 32 + i4] =
            *(const float4*)(p1 + ((size_t)b * 3 + k3) * N_ + n0 + i4);
    } else if (t < 120) {
        int i4 = (t - 24) * 4;
        *(float4*)&wlsq[i4] = *(const float4*)(Wpos + i4);
    }
    __syncthreads();

    #pragma unroll
    for (int k = 0; k < 2; ++k) {
        int s = t + k * 512;
        int c = s >> 3, n4 = (s & 7) * 4;
        float4 xv = *(const float4*)(x1 + ((size_t)b * C_ + c) * N_ + n0 + n4);
        float w0 = wlsq[c * 3 + 0], w1 = wlsq[c * 3 + 1], w2 = wlsq[c * 3 + 2];
        const float* xa = &xv.x;
        #pragma unroll
        for (int j = 0; j < 4; ++j) {
            float pos = w0 * ppq[n4 + j] + w1 * ppq[32 + n4 + j] + w2 * ppq[64 + n4 + j];
            xq[(n4 + j) * 136 + c] = (bf16)(xa[j] + pos);
        }
    }
    __syncthreads();

    {   // 8 waves: band = w&1 (16 q-points), dt-quarter = w>>1 (2 of 8 dts)
        const int colq = lane & 15, quadq = lane >> 4;
        const int nlq = (w & 1) * 16 + colq;
        bf16x8 bxq[4];
        #pragma unroll
        for (int cs = 0; cs < 4; ++cs)
            bxq[cs] = *(const bf16x8*)&xq[nlq * 136 + cs * 32 + quadq * 8];
        __syncthreads();               // fragment reads done before Q overwrites xq
        const int dt0 = (w >> 1) * 2;
        #pragma unroll
        for (int di = 0; di < 2; ++di) {
            int dt = dt0 + di;
            f32x4 acc = {0.f, 0.f, 0.f, 0.f};
            #pragma unroll
            for (int cs = 0; cs < 4; ++cs) {
                bf16x8 wf = *(const bf16x8*)(Wb + (dt * 16 + colq) * 128 + cs * 32 + quadq * 8);
                acc = MFMA16(bxq[cs], wf, acc);       // D[q-rows][c-cols]
            }
            #pragma unroll
            for (int r = 0; r < 4; ++r)
                xq[((w & 1) * 16 + quadq * 4 + r) * 136 + dt * 16 + colq] = (bf16)acc[r];
        }
        __syncthreads();               // Q tile complete (pre-scaled by KS)
    }

    // Q fragments: lane col = query (0..31), k = cs*16 + hi*8 + j
    bf16x8 qf[8];
    #pragma unroll
    for (int cs = 0; cs < 8; ++cs)
        qf[cs] = *(const bf16x8*)&xq[col * 136 + cs * 16 + hi * 8];
    asm volatile("s_waitcnt lgkmcnt(0)" ::: "memory");
    __builtin_amdgcn_sched_barrier(0);
    __builtin_amdgcn_s_barrier();      // qf reads retired before staging lands
    // =====================================================================

    f32x16 oacc[4];
    #pragma unroll
    for (int i = 0; i < 4; ++i)
        #pragma unroll
        for (int j = 0; j < 16; ++j) oacc[i][j] = 0.f;
    f32x16 Z;
    #pragma unroll
    for (int j = 0; j < 16; ++j) Z[j] = 0.f;
    float lacc = 0.f;

    const int key_l = (w << 5) + col;          // this wave's key (0..255)
    const int kxor = (key_l & 15) << 4;

    // ---- precomputed LDS read addresses ----
    int kaddr[8];
    #pragma unroll
    for (int cs = 0; cs < 8; ++cs)
        kaddr[cs] = key_l * 256 + (((((cs << 1) + hi)) << 4) ^ kxor);
    // V: c0 = col; slot (w*4+hi) ^ (c&31); ct advances by 32 c = +16384 B
    const int vaddrA = 65536 + col * 512 + ((((w << 2) + hi) ^ col) << 4);
    const int vaddrB = vaddrA ^ 32;            // slot +2

    // ---- staging: wave w covers segs w*512..+511 of each tile (8 glls) ----
    const bf16* Kchunk = Kbase;
    const bf16* Vchunk = Vbase;
    int koff[8], voff[8];
    #pragma unroll
    for (int i = 0; i < 8; ++i) {
        int g = (w << 9) + (i << 6) + lane;
        int krow = g >> 4;                     // key (16 segs/row) = w*32..+31
        koff[i] = krow * C_ + ((g & 15) ^ (krow & 15)) * 8;
        int vrow = g >> 5;                     // channel (32 segs/row) = w*16..+15
        voff[i] = vrow * M_ + ((g & 31) ^ (vrow & 31)) * 8;
    }

    auto stageK = [&]() {
        #pragma unroll
        for (int i = 0; i < 8; ++i)
            gll16(Kchunk + koff[i], (bf16*)smem + (w << 12) + (i << 9) + lane * 8);
        Kchunk += 256 * C_;                    // next 256-key chunk
    };
    auto stageV = [&]() {
        #pragma unroll
        for (int i = 0; i < 8; ++i)
            gll16(Vchunk + voff[i], (bf16*)(smem + 65536) + (w << 12) + (i << 9) + lane * 8);
        Vchunk += 256;
    };

    stageK();                                  // K0: 8 glls (oldest)
    stageV();                                  // V0: 8 glls

    #pragma unroll 1
    for (int ch = 0; ch < 16; ++ch) {
        // own K(ch) landed (oldest 8 of 16); V(ch) may still fly
        asm volatile("s_waitcnt vmcnt(8)" ::: "memory");
        __builtin_amdgcn_sched_barrier(0);

        // ---- S = K Q (swapped), wave-private kb: NO barrier ----
        __builtin_amdgcn_s_setprio(1);
        bf16x8 kf0 = *(const bf16x8*)(smem + kaddr[0]);
        f32x16 sacc = MFMA32(kf0, qf[0], Z);
        #pragma unroll
        for (int cs = 1; cs < 8; ++cs) {
            bf16x8 kf = *(const bf16x8*)(smem + kaddr[cs]);
            sacc = MFMA32(kf, qf[cs], sacc);
        }
        __builtin_amdgcn_s_setprio(0);

        // own kb reads retired -> safe to restage own rows (single buffer)
        asm volatile("s_waitcnt lgkmcnt(0)" ::: "memory");
        __builtin_amdgcn_sched_barrier(0);
        if (ch < 15) stageK();

        // ---- P = exp2(S) (KS pre-folded) ----
        float p[16];
        #pragma unroll
        for (int r = 0; r < 16; ++r)
            p[r] = __builtin_amdgcn_exp2f(sacc[r]);
        {
            float s01 = (p[0] + p[1]) + (p[2] + p[3]);
            float s23 = (p[4] + p[5]) + (p[6] + p[7]);
            float s45 = (p[8] + p[9]) + (p[10] + p[11]);
            float s67 = (p[12] + p[13]) + (p[14] + p[15]);
            lacc += (s01 + s23) + (s45 + s67);
        }
        unsigned W0 = cvtpk(p[0], p[1]),  W1 = cvtpk(p[2], p[3]);
        unsigned W2 = cvtpk(p[4], p[5]),  W3 = cvtpk(p[6], p[7]);
        unsigned W4 = cvtpk(p[8], p[9]),  W5 = cvtpk(p[10], p[11]);
        unsigned W6 = cvtpk(p[12], p[13]), W7 = cvtpk(p[14], p[15]);
        uint4 u0, u1;
#if __has_builtin(__builtin_amdgcn_permlane32_swap)
        u32x2 r0 = __builtin_amdgcn_permlane32_swap(W0, W2, false, false);
        u0.x = r0[0]; u0.z = r0[1];
        u32x2 r1 = __builtin_amdgcn_permlane32_swap(W1, W3, false, false);
        u0.y = r1[0]; u0.w = r1[1];
        u32x2 r2 = __builtin_amdgcn_permlane32_swap(W4, W6, false, false);
        u1.x = r2[0]; u1.z = r2[1];
        u32x2 r3 = __builtin_amdgcn_permlane32_swap(W5, W7, false, false);
        u1.y = r3[0]; u1.w = r3[1];
#else
        unsigned X0 = hi ? W0 : W2, X1 = hi ? W1 : W3;
        unsigned Y0 = hi ? W4 : W6, Y1 = hi ? W5 : W7;
        X0 = __shfl_xor(X0, 32, 64);  X1 = __shfl_xor(X1, 32, 64);
        Y0 = __shfl_xor(Y0, 32, 64);  Y1 = __shfl_xor(Y1, 32, 64);
        u0.x = hi ? X0 : W0;  u0.y = hi ? X1 : W1;
        u0.z = hi ? W2 : X0;  u0.w = hi ? W3 : X1;
        u1.x = hi ? Y0 : W4;  u1.y = hi ? Y1 : W5;
        u1.z = hi ? W6 : Y0;  u1.w = hi ? W7 : Y1;
#endif
        bf16x8 af0 = __builtin_bit_cast(bf16x8, u0);   // local keys hi*8..+7
        bf16x8 af1 = __builtin_bit_cast(bf16x8, u1);   // local keys 16+hi*8..+7

        // V(ch) landed (oldest 8; K(ch+1) stays in flight); publish via barrier
        if (ch < 15) asm volatile("s_waitcnt vmcnt(8)" ::: "memory");
        else         asm volatile("s_waitcnt vmcnt(0)" ::: "memory");
        __builtin_amdgcn_sched_barrier(0);
        __builtin_amdgcn_s_barrier();

        // ---- O += P V^T (this wave's 32 keys, all 128 c) ----
        __builtin_amdgcn_s_setprio(1);
        #pragma unroll
        for (int ct = 0; ct < 4; ++ct) {
            bf16x8 vf0 = *(const bf16x8*)(smem + ct * 16384 + vaddrA);
            bf16x8 vf1 = *(const bf16x8*)(smem + ct * 16384 + vaddrB);
            oacc[ct] = MFMA32(af0, vf0, oacc[ct]);
            oacc[ct] = MFMA32(af1, vf1, oacc[ct]);
        }
        __builtin_amdgcn_s_setprio(0);

        // all waves' vb reads retired before anyone restages vb
        asm volatile("s_waitcnt lgkmcnt(0)" ::: "memory");
        __builtin_amdgcn_sched_barrier(0);
        __builtin_amdgcn_s_barrier();
        if (ch < 15) stageV();
    }

    __builtin_amdgcn_s_barrier();   // reuse smem for the merge

    // ---- cross-wave merge of the 8 key-group partials ----
    float* obuf = (float*)smem;                 // [8 kg][32 q][128 c]  128 KB
    float* lps  = (float*)(smem + 131072);      // [8 kg][32 q]  1 KB

    lacc += __shfl_xor(lacc, 32, 64);           // + other hi-half's 16 keys
    if (hi == 0) lps[(w << 5) + col] = lacc;

    #pragma unroll
    for (int ct = 0; ct < 4; ++ct)
        #pragma unroll
        for (int r = 0; r < 16; ++r) {
            int q = (r & 3) + ((r >> 2) << 3) + (hi << 2);
            obuf[w * 4096 + q * 128 + (ct << 5) + col] = oacc[ct][r];
        }
    __syncthreads();

    const int c2 = lane << 1;                   // 2 channels per lane
    #pragma unroll
    for (int j = 0; j < 4; ++j) {
        int q = (w << 2) + j;                   // wave w finalizes queries w*4..+3
        float s0 = 0.f, s1 = 0.f;
        float lsum = 0.f;
        #pragma unroll
        for (int p8 = 0; p8 < 8; ++p8) {
            float2 v = *(const float2*)&obuf[p8 * 4096 + q * 128 + c2];
            s0 += v.x; s1 += v.y;
            lsum += lps[p8 * 32 + q];
        }
        float linv = 1.0f / lsum;
        int n = n0 + q;
        float o0 = s0 * linv + x1[((size_t)b * C_ + c2) * N_ + n];
        float o1 = s1 * linv + x1[((size_t)b * C_ + c2 + 1) * N_ + n];
        *(float2*)&out[((size_t)b * N_ + n) * C_ + c2] = make_float2(o0, o1);
    }
}

// ---------------------------------------------------------------------------
extern "C" void kernel_launch(void* const* d_in, const int* in_sizes, int n_in,
                              void* d_out, int out_size, void* d_ws, size_t ws_size,
                              hipStream_t stream) {
    const float* x1   = (const float*)d_in[0];
    const float* p1   = (const float*)d_in[1];
    const float* x2   = (const float*)d_in[2];
    const float* p2   = (const float*)d_in[3];
    const float* Wq   = (const float*)d_in[4];
    const float* Wk   = (const float*)d_in[5];
    const float* Wv   = (const float*)d_in[6];
    const float* Wpos = (const float*)d_in[7];
    float* out = (float*)d_out;

    // d_ws layout: Wb (128 KB region) | Kt [B][M][C] 4 MB | Vt [B][C][M] 4 MB
    bf16* Wb = (bf16*)d_ws;
    bf16* Kt = Wb + 65536;
    bf16* Vt = Kt + (size_t)B_ * N_ * C_;

    wcvt_kernel<<<dim3(48), dim3(256), 0, stream>>>(Wq, Wk, Wv, Wb);
    kvproj_kernel<<<dim3(128, B_), dim3(256), 0, stream>>>(
        x2, p2, Wb, Wpos, Kt, Vt);
    attn_kernel<<<dim3(512), dim3(512), 0, stream>>>(
        Kt, Vt, x1, p1, Wb, Wpos, out);
}